// Round 5
// baseline (277.930 us; speedup 1.0000x reference)
//
#include <hip/hip_runtime.h>

typedef __attribute__((ext_vector_type(8))) short short8_t;  // 8 bf16 (4 VGPRs)
typedef __attribute__((ext_vector_type(4))) short short4_t;  // 4 bf16 (2 VGPRs)
typedef __attribute__((ext_vector_type(4))) float float4_t;  // MFMA C/D
typedef unsigned short u16;
typedef unsigned int u32;
typedef unsigned long long u64;

// ---------- helpers ----------
__device__ inline u16 f2bf(float x) {
  union { float f; u32 u; } v; v.f = x;
  u32 r = v.u + 0x7FFFu + ((v.u >> 16) & 1u);  // round-to-nearest-even
  return (u16)(r >> 16);
}
__device__ inline u32 packbf(float a, float b) {
  return (u32)f2bf(a) | ((u32)f2bf(b) << 16);
}
// async global->LDS DMA, 16B per lane; lds dest = wave-uniform base + lane*16
__device__ inline void async16(const u16* g, u16* l) {
  __builtin_amdgcn_global_load_lds(
      (const __attribute__((address_space(1))) unsigned int*)g,
      (__attribute__((address_space(3))) unsigned int*)l, 16, 0, 0);
}

#if __has_builtin(__builtin_amdgcn_mfma_f32_16x16x16bf16_1k)
#define HAVE_M16 1
__device__ inline float4_t mfma16(short4_t a, short4_t b, float4_t c) {
  return __builtin_amdgcn_mfma_f32_16x16x16bf16_1k(a, b, c, 0, 0, 0);
}
#else
#define HAVE_M16 0
#endif

// ---------- fused prologue: X fp32->bf16 (blocks 0..4095), W transposes (4096..8191) ----------
__global__ __launch_bounds__(256) void prologue(const float* __restrict__ X,
                                                const float* __restrict__ Wq, const float* __restrict__ Wk,
                                                const float* __restrict__ Wv, const float* __restrict__ Wo,
                                                u16* __restrict__ Xb, u16* __restrict__ WqkvT,
                                                u16* __restrict__ WoT) {
  __shared__ float tls[32][33];
  int bid = blockIdx.x;
  if (bid < 4096) {
    int i = bid * 256 + threadIdx.x;  // one float4 per thread
    float4_t x = ((const float4_t*)X)[i];
    union { u32 u[2]; u64 ll; } o;
    o.u[0] = packbf(x[0], x[1]);
    o.u[1] = packbf(x[2], x[3]);
    ((u64*)Xb)[i] = o.ll;
  } else {
    int t = bid - 4096;
    int mat = t >> 10, tile = t & 1023;
    const float* W = (mat == 0) ? Wq : (mat == 1) ? Wk : (mat == 2) ? Wv : Wo;
    u16* WT = (mat < 3) ? WqkvT + ((size_t)mat << 20) : WoT;
    int tx = threadIdx.x & 31, ty = threadIdx.x >> 5;  // 32 x 8
    int c0 = (tile & 31) * 32, r0 = (tile >> 5) * 32;  // r0: k, c0: n
    #pragma unroll
    for (int i = 0; i < 4; ++i)
      tls[ty + i * 8][tx] = W[(r0 + ty + i * 8) * 1024 + c0 + tx];
    __syncthreads();
    #pragma unroll
    for (int i = 0; i < 4; ++i)
      WT[(size_t)(c0 + ty + i * 8) * 1024 + r0 + tx] = f2bf(tls[tx][ty + i * 8]);
  }
}

// ---------- GEMM: 128x128 C-tile, 4 waves each 64x64, BK=64 ----------
// 1D grid with L2-locality swizzle (mode 4: 16-m x n panels). LDS staged via
// global_load_lds; XOR chunk swizzle applied at global SOURCE address.
// mode 4 (fused QKV, 768 blocks): col block 0->Q(x0.125) o0 [B,H,S,64], 1->K o1,
//   2->V o2 [B,H,64,S] (transposed). mode 3 (O-proj, 256 blocks): fp32 out o0.
__global__ __launch_bounds__(256) void gemm128(const u16* __restrict__ A, const u16* __restrict__ BT,
                                               const float* __restrict__ bias0, const float* __restrict__ bias1,
                                               const float* __restrict__ bias2,
                                               void* __restrict__ o0, void* __restrict__ o1, void* __restrict__ o2,
                                               int mode) {
  __shared__ __align__(16) u16 Als[128 * 64];  // 16 KB
  __shared__ __align__(16) u16 Bls[128 * 64];  // 16 KB
  int g = blockIdx.x, m0t, n0t;
  if (mode == 4) {  // 768 blocks: panels of 16 m-tiles x 24 n-tiles
    int mh = g / 384, r = g - mh * 384;
    n0t = r >> 4;
    m0t = mh * 16 + (r & 15);
  } else {          // 256 blocks
    m0t = g & 31;
    n0t = g >> 5;
  }
  const int m0 = m0t * 128, n0 = n0t * 128;
  const int lane = threadIdx.x & 63, wave = threadIdx.x >> 6;
  const int quad = lane >> 4, c = lane & 15;
  const int wm = wave >> 1, wn = wave & 1;

  // staging: call q stages rows wave*32+q*8 .. +7 (8 rows x 8 chunks = 64 lanes)
  const int srow = lane >> 3, schunk = lane & 7;
  int soff[4];  u16 *lA[4], *lB[4];
  #pragma unroll
  for (int q = 0; q < 4; ++q) {
    int r = wave * 32 + q * 8 + srow;
    soff[q] = r * 1024 + ((schunk ^ (r & 7)) << 3);
    lA[q] = &Als[(wave * 32 + q * 8) * 64 + lane * 8];
    lB[q] = &Bls[(wave * 32 + q * 8) * 64 + lane * 8];
  }
  const u16* gA = A + (size_t)m0 * 1024;
  const u16* gB = BT + (size_t)n0 * 1024;

  int ar[2][4], br[2][4];
  #pragma unroll
  for (int ko = 0; ko < 2; ++ko) {
    #pragma unroll
    for (int i = 0; i < 4; ++i) {
      int rowa = wm * 64 + i * 16 + c;
      ar[ko][i] = rowa * 64 + (((ko * 4 + quad) ^ (rowa & 7)) << 3);
      int rowb = wn * 64 + i * 16 + c;
      br[ko][i] = rowb * 64 + (((ko * 4 + quad) ^ (rowb & 7)) << 3);
    }
  }

  float4_t acc[4][4] = {};
  for (int k0 = 0; k0 < 1024; k0 += 64) {
    #pragma unroll
    for (int q = 0; q < 4; ++q) async16(gA + soff[q] + k0, lA[q]);
    #pragma unroll
    for (int q = 0; q < 4; ++q) async16(gB + soff[q] + k0, lB[q]);
    __syncthreads();
    #pragma unroll
    for (int ko = 0; ko < 2; ++ko) {
      short8_t af[4], bfr[4];
      #pragma unroll
      for (int i = 0; i < 4; ++i) af[i] = *(const short8_t*)&Als[ar[ko][i]];
      #pragma unroll
      for (int j = 0; j < 4; ++j) bfr[j] = *(const short8_t*)&Bls[br[ko][j]];
      #pragma unroll
      for (int i = 0; i < 4; ++i)
        #pragma unroll
        for (int j = 0; j < 4; ++j)
          acc[i][j] = __builtin_amdgcn_mfma_f32_16x16x32_bf16(af[i], bfr[j], acc[i][j], 0, 0, 0);
    }
    __syncthreads();
  }

  const int mrow = m0 + wm * 64, ncol = n0 + wn * 64;
  if (mode == 3) {
    float* o = (float*)o0;
    #pragma unroll
    for (int i = 0; i < 4; ++i) {
      #pragma unroll
      for (int j = 0; j < 4; ++j) {
        int colb = ncol + j * 16 + c;
        float bv = bias0[colb];
        int rowb = mrow + i * 16 + quad * 4;
        #pragma unroll
        for (int r = 0; r < 4; ++r)
          o[(size_t)(rowb + r) * 1024 + colb] = acc[i][j][r] + bv;
      }
    }
  } else {
    #pragma unroll
    for (int j = 0; j < 4; ++j) {
      int colb = ncol + j * 16 + c;     // 0..3071
      int which = colb >> 10;           // 0:Q 1:K 2:V (uniform per j)
      int n1 = colb & 1023, h = n1 >> 6, d = n1 & 63;
      const float* bp = (which == 0) ? bias0 : (which == 1 ? bias1 : bias2);
      float bv = bp[n1];
      #pragma unroll
      for (int i = 0; i < 4; ++i) {
        int rowb = mrow + i * 16 + quad * 4;
        int b = rowb >> 11, s = rowb & 2047;
        if (which == 2) {
          u16* o = (u16*)o2 + (((size_t)(b * 16 + h) * 64 + d) * 2048 + s);
          union { u32 u[2]; u64 ll; } ov;
          ov.u[0] = packbf(acc[i][j][0] + bv, acc[i][j][1] + bv);
          ov.u[1] = packbf(acc[i][j][2] + bv, acc[i][j][3] + bv);
          *(u64*)o = ov.ll;
        } else {
          float sc = (which == 0) ? 0.125f : 1.0f;
          u16* o = (u16*)((which == 0) ? o0 : o1);
          #pragma unroll
          for (int r = 0; r < 4; ++r)
            o[(((size_t)(b * 16 + h) * 2048 + (s + r)) << 6) + d] = f2bf((acc[i][j][r] + bv) * sc);
        }
      }
    }
  }
}

// ---------- softmax: S^T C-layout fragments -> p[8] + row-sum (fixed-base exp) ----------
__device__ inline void softmax_p(float4_t s0, float4_t s1, float4_t mpl0, float4_t mpl1,
                                 bool diag, int kbase, int quad, int c, int qg,
                                 float& lacc, float* p) {
  const float LOG2E = 1.4426950408889634f;
  #pragma unroll
  for (int e = 0; e < 8; ++e) {
    float sv = (e < 4) ? s0[e] : s1[e - 4];
    float ml = (e < 4) ? mpl0[e] : mpl1[e - 4];
    float arg = __builtin_fmaf(sv, LOG2E, ml);
    if (diag) {
      int kpos = kbase + ((e >> 2) << 4) + quad * 4 + (e & 3);
      arg = (kpos > qg) ? -50.0f : arg;   // exp2(-50) ~ 9e-16 ~ 0
    }
    float pe = exp2f(arg);
    p[e] = pe;
    lacc += pe;
  }
}

#if !HAVE_M16
// fallback: P^T C-layout -> 16x16x32 B-operand layout via packed-bf16 shuffles
__device__ inline short8_t p_to_b32(const float* p, int quad, int c) {
  u32 pk0[2] = {packbf(p[0], p[1]), packbf(p[2], p[3])};
  u32 pk1[2] = {packbf(p[4], p[5]), packbf(p[6], p[7])};
  int base = ((quad & 1) * 2) * 16 + c;
  union { u32 u[4]; short8_t v; } pf;
  #pragma unroll
  for (int x = 0; x < 4; ++x) {
    int src = base + ((x >> 1) << 4);
    int v0 = __shfl((int)pk0[x & 1], src);
    int v1 = __shfl((int)pk1[x & 1], src);
    pf.u[x] = (quad < 2) ? (u32)v0 : (u32)v1;
  }
  return pf.v;
}
#endif

// ---------- flash attention ----------
// Q,K: [B,H,S,64] bf16 (Q pre-scaled 1/8); VT: [B,H,64,S]; ctx: [B,S,1024] bf16.
// Grid 1024, uniform work: block handles query-units {pr, 63-pr} sequentially (65 k-tiles
// total), 4 waves split K strided-by-4 (fixed-base softmax -> additive partials), combine
// via 17KB LDS. XCD affinity: g&7 pins each bh's K/V into one XCD's L2.
// PV uses v_mfma_f32_16x16x16_bf16: its B-operand layout [k=quad*4+j][n=c] EQUALS the
// S^T C/D layout (row=quad*4+r, col=c) -> in-lane pack, zero cross-lane shuffles.
__global__ __launch_bounds__(256) void attn_kernel(const u16* __restrict__ Q, const u16* __restrict__ K,
                                                   const u16* __restrict__ VT, const float* __restrict__ mask,
                                                   u16* __restrict__ ctx) {
  __shared__ float cmb[4][64][17];
  const float C1 = 10000.0f * 1.4426950408889634f;
  int w = threadIdx.x >> 6, lane = threadIdx.x & 63;
  int quad = lane >> 4, c = lane & 15;
  int g = blockIdx.x;
  int bh = (g & 7) * 4 + ((g >> 3) & 3);   // XCD-affine
  int pr = g >> 5;                          // 0..31
  int b = bh >> 4, h = bh & 15;
  const u16* Kp = K + ((size_t)bh << 17);
  const u16* Vp = VT + ((size_t)bh << 17);
  const float* mp = mask + (b << 11);

  #pragma unroll 1
  for (int ph = 0; ph < 2; ++ph) {
    int u = ph ? (63 - pr) : pr;
    int q0 = u << 5;
    const u16* Qp = Q + (((size_t)bh * 2048 + q0 + c) << 6) + quad * 8;
    short8_t qA0 = *(const short8_t*)(Qp);
    short8_t qA1 = *(const short8_t*)(Qp + 32);
    short8_t qB0 = *(const short8_t*)(Qp + 1024);
    short8_t qB1 = *(const short8_t*)(Qp + 1024 + 32);
    float4_t OA[4] = {}, OB[4] = {};
    float lA = 0.0f, lB = 0.0f;
    int qgA = q0 + c, qgB = q0 + 16 + c;
    for (int t = w; t <= u; t += 4) {
      int kbase = t << 5;
      const u16* kp = Kp + (((size_t)kbase + c) << 6) + quad * 8;
      short8_t ka0 = *(const short8_t*)(kp);
      short8_t ka1 = *(const short8_t*)(kp + 32);
      short8_t kb0 = *(const short8_t*)(kp + 1024);
      short8_t kb1 = *(const short8_t*)(kp + 1024 + 32);
      float4_t mv0 = *(const float4_t*)(mp + kbase + quad * 4);
      float4_t mv1 = *(const float4_t*)(mp + kbase + 16 + quad * 4);
      float4_t mpl0 = (mv0 - 1.0f) * C1;  // (1-m)*-10000*log2e
      float4_t mpl1 = (mv1 - 1.0f) * C1;
      bool diag = (t == u);
      float4_t sA0 = {}, sA1 = {}, sB0 = {}, sB1 = {};
      sA0 = __builtin_amdgcn_mfma_f32_16x16x32_bf16(ka0, qA0, sA0, 0, 0, 0);
      sA0 = __builtin_amdgcn_mfma_f32_16x16x32_bf16(ka1, qA1, sA0, 0, 0, 0);
      sA1 = __builtin_amdgcn_mfma_f32_16x16x32_bf16(kb0, qA0, sA1, 0, 0, 0);
      sA1 = __builtin_amdgcn_mfma_f32_16x16x32_bf16(kb1, qA1, sA1, 0, 0, 0);
      sB0 = __builtin_amdgcn_mfma_f32_16x16x32_bf16(ka0, qB0, sB0, 0, 0, 0);
      sB0 = __builtin_amdgcn_mfma_f32_16x16x32_bf16(ka1, qB1, sB0, 0, 0, 0);
      sB1 = __builtin_amdgcn_mfma_f32_16x16x32_bf16(kb0, qB0, sB1, 0, 0, 0);
      sB1 = __builtin_amdgcn_mfma_f32_16x16x32_bf16(kb1, qB1, sB1, 0, 0, 0);
      float pA[8], pB[8];
      softmax_p(sA0, sA1, mpl0, mpl1, diag, kbase, quad, c, qgA, lA, pA);
      softmax_p(sB0, sB1, mpl0, mpl1, diag, kbase, quad, c, qgB, lB, pB);
#if HAVE_M16
      union { u32 u[2]; short4_t v; } kA0, kA1, kB0, kB1;
      kA0.u[0] = packbf(pA[0], pA[1]); kA0.u[1] = packbf(pA[2], pA[3]);
      kA1.u[0] = packbf(pA[4], pA[5]); kA1.u[1] = packbf(pA[6], pA[7]);
      kB0.u[0] = packbf(pB[0], pB[1]); kB0.u[1] = packbf(pB[2], pB[3]);
      kB1.u[0] = packbf(pB[4], pB[5]); kB1.u[1] = packbf(pB[6], pB[7]);
      const u16* vp = Vp + (size_t)c * 2048 + kbase + quad * 4;
      #pragma unroll
      for (int d = 0; d < 4; ++d) {
        short4_t v0 = *(const short4_t*)(vp + d * 16 * 2048);
        short4_t v1 = *(const short4_t*)(vp + d * 16 * 2048 + 16);
        OA[d] = mfma16(v0, kA0.v, OA[d]);
        OA[d] = mfma16(v1, kA1.v, OA[d]);
        OB[d] = mfma16(v0, kB0.v, OB[d]);
        OB[d] = mfma16(v1, kB1.v, OB[d]);
      }
#else
      short8_t pfA = p_to_b32(pA, quad, c);
      short8_t pfB = p_to_b32(pB, quad, c);
      const u16* vp = Vp + (size_t)c * 2048 + kbase + quad * 8;
      #pragma unroll
      for (int d = 0; d < 4; ++d) {
        short8_t vf = *(const short8_t*)(vp + d * 16 * 2048);
        OA[d] = __builtin_amdgcn_mfma_f32_16x16x32_bf16(vf, pfA, OA[d], 0, 0, 0);
        OB[d] = __builtin_amdgcn_mfma_f32_16x16x32_bf16(vf, pfB, OB[d], 0, 0, 0);
      }
#endif
    }
    // ---- combine half A ----
    float* cw = &cmb[w][lane][0];
    #pragma unroll
    for (int d = 0; d < 4; ++d)
      #pragma unroll
      for (int r = 0; r < 4; ++r) cw[d * 4 + r] = OA[d][r];
    cw[16] = lA;
    __syncthreads();
    {
      float4_t sA = {};
      float la = 0.0f;
      #pragma unroll
      for (int w2 = 0; w2 < 4; ++w2) {
        const float* cr = &cmb[w2][lane][0];
        #pragma unroll
        for (int r = 0; r < 4; ++r) sA[r] += cr[w * 4 + r];
        la += cr[16];
      }
      la += __shfl_xor(la, 16); la += __shfl_xor(la, 32);
      float rA = 1.0f / la;
      u16* opA = ctx + ((size_t)(b * 2048 + q0 + c) * 1024 + h * 64 + w * 16 + quad * 4);
      union { u32 uu[2]; u64 ll; } ov;
      ov.uu[0] = packbf(sA[0] * rA, sA[1] * rA);
      ov.uu[1] = packbf(sA[2] * rA, sA[3] * rA);
      *(u64*)opA = ov.ll;
    }
    __syncthreads();
    // ---- combine half B ----
    #pragma unroll
    for (int d = 0; d < 4; ++d)
      #pragma unroll
      for (int r = 0; r < 4; ++r) cw[d * 4 + r] = OB[d][r];
    cw[16] = lB;
    __syncthreads();
    {
      float4_t sB = {};
      float lb = 0.0f;
      #pragma unroll
      for (int w2 = 0; w2 < 4; ++w2) {
        const float* cr = &cmb[w2][lane][0];
        #pragma unroll
        for (int r = 0; r < 4; ++r) sB[r] += cr[w * 4 + r];
        lb += cr[16];
      }
      lb += __shfl_xor(lb, 16); lb += __shfl_xor(lb, 32);
      float rB = 1.0f / lb;
      u16* opB = ctx + ((size_t)(b * 2048 + q0 + 16 + c) * 1024 + h * 64 + w * 16 + quad * 4);
      union { u32 uu[2]; u64 ll; } ov;
      ov.uu[0] = packbf(sB[0] * rB, sB[1] * rB);
      ov.uu[1] = packbf(sB[2] * rB, sB[3] * rB);
      *(u64*)opB = ov.ll;
    }
    __syncthreads();  // protect LDS reuse by next phase
  }
}

// ---------- launch ----------
extern "C" void kernel_launch(void* const* d_in, const int* in_sizes, int n_in,
                              void* d_out, int out_size, void* d_ws, size_t ws_size,
                              hipStream_t stream) {
  const float* X    = (const float*)d_in[0];
  const float* mask = (const float*)d_in[1];
  const float* Wq   = (const float*)d_in[2];
  const float* bq   = (const float*)d_in[3];
  const float* Wk   = (const float*)d_in[4];
  const float* bk   = (const float*)d_in[5];
  const float* Wv   = (const float*)d_in[6];
  const float* bv   = (const float*)d_in[7];
  const float* Wo   = (const float*)d_in[8];
  const float* bo   = (const float*)d_in[9];

  char* w = (char*)d_ws;
  u16* Xb     = (u16*)(w);                 // 8 MB  [4096,1024] bf16
  u16* WqkvT  = (u16*)(w + (8ull  << 20)); // 6 MB  [3072,1024] bf16 (Q|K|V transposed)
  u16* WoT    = (u16*)(w + (14ull << 20)); // 2 MB  [1024,1024] bf16
  u16* Qb     = (u16*)(w + (16ull << 20)); // 8 MB [B,H,S,64]
  u16* Kb     = (u16*)(w + (24ull << 20)); // 8 MB [B,H,S,64]
  u16* VTb    = (u16*)(w + (32ull << 20)); // 8 MB [B,H,64,S]
  u16* Ctx    = (u16*)(w + (40ull << 20)); // 8 MB [4096,1024]

  prologue<<<8192, 256, 0, stream>>>(X, Wq, Wk, Wv, Wo, Xb, WqkvT, WoT);
  gemm128<<<768, 256, 0, stream>>>(Xb, WqkvT, bq, bk, bv, Qb, Kb, VTb, 4);
  attn_kernel<<<1024, 256, 0, stream>>>(Qb, Kb, VTb, mask, Ctx);
  gemm128<<<256, 256, 0, stream>>>(Ctx, WoT, bo, bo, bo, d_out, d_out, d_out, 3);
}

// Round 6
// 230.740 us; speedup vs baseline: 1.2045x; 1.2045x over previous
//
#include <hip/hip_runtime.h>

typedef __attribute__((ext_vector_type(8))) short short8_t;  // 8 bf16 (4 VGPRs)
typedef __attribute__((ext_vector_type(4))) float float4_t;  // MFMA C/D
typedef unsigned short u16;
typedef unsigned int u32;
typedef unsigned long long u64;

// ---------- helpers ----------
__device__ inline u16 f2bf(float x) {
  union { float f; u32 u; } v; v.f = x;
  u32 r = v.u + 0x7FFFu + ((v.u >> 16) & 1u);  // round-to-nearest-even
  return (u16)(r >> 16);
}
__device__ inline u32 packbf(float a, float b) {
  return (u32)f2bf(a) | ((u32)f2bf(b) << 16);
}
// async global->LDS DMA, 16B per lane; lds dest = wave-uniform base + lane*16
__device__ inline void async16(const u16* g, u16* l) {
  __builtin_amdgcn_global_load_lds(
      (const __attribute__((address_space(1))) unsigned int*)g,
      (__attribute__((address_space(3))) unsigned int*)l, 16, 0, 0);
}

// ---------- fused prologue: X fp32->bf16 (blocks 0..4095), W transposes (4096..8191) ----------
__global__ __launch_bounds__(256) void prologue(const float* __restrict__ X,
                                                const float* __restrict__ Wq, const float* __restrict__ Wk,
                                                const float* __restrict__ Wv, const float* __restrict__ Wo,
                                                u16* __restrict__ Xb, u16* __restrict__ WqkvT,
                                                u16* __restrict__ WoT) {
  __shared__ float tls[32][33];
  int bid = blockIdx.x;
  if (bid < 4096) {
    int i = bid * 256 + threadIdx.x;  // one float4 per thread
    float4_t x = ((const float4_t*)X)[i];
    union { u32 u[2]; u64 ll; } o;
    o.u[0] = packbf(x[0], x[1]);
    o.u[1] = packbf(x[2], x[3]);
    ((u64*)Xb)[i] = o.ll;
  } else {
    int t = bid - 4096;
    int mat = t >> 10, tile = t & 1023;
    const float* W = (mat == 0) ? Wq : (mat == 1) ? Wk : (mat == 2) ? Wv : Wo;
    u16* WT = (mat < 3) ? WqkvT + ((size_t)mat << 20) : WoT;
    int tx = threadIdx.x & 31, ty = threadIdx.x >> 5;  // 32 x 8
    int c0 = (tile & 31) * 32, r0 = (tile >> 5) * 32;  // r0: k, c0: n
    #pragma unroll
    for (int i = 0; i < 4; ++i)
      tls[ty + i * 8][tx] = W[(r0 + ty + i * 8) * 1024 + c0 + tx];
    __syncthreads();
    #pragma unroll
    for (int i = 0; i < 4; ++i)
      WT[(size_t)(c0 + ty + i * 8) * 1024 + r0 + tx] = f2bf(tls[tx][ty + i * 8]);
  }
}

// ---------- GEMM: 128x128 C-tile, 4 waves each 64x64, BK=64 ----------
// 1D grid with L2-locality swizzle (mode 4: 16-m x n panels). LDS staged via
// global_load_lds; XOR chunk swizzle applied at global SOURCE address.
// mode 4 (fused QKV, 768 blocks): col block 0->Q(x0.125) o0 [B,H,S,64], 1->K o1,
//   2->V o2 [B,H,64,S] (transposed). mode 3 (O-proj, 256 blocks): fp32 out o0.
__global__ __launch_bounds__(256) void gemm128(const u16* __restrict__ A, const u16* __restrict__ BT,
                                               const float* __restrict__ bias0, const float* __restrict__ bias1,
                                               const float* __restrict__ bias2,
                                               void* __restrict__ o0, void* __restrict__ o1, void* __restrict__ o2,
                                               int mode) {
  __shared__ __align__(16) u16 Als[128 * 64];  // 16 KB
  __shared__ __align__(16) u16 Bls[128 * 64];  // 16 KB
  int g = blockIdx.x, m0t, n0t;
  if (mode == 4) {  // 768 blocks: panels of 16 m-tiles x 24 n-tiles
    int mh = g / 384, r = g - mh * 384;
    n0t = r >> 4;
    m0t = mh * 16 + (r & 15);
  } else {          // 256 blocks
    m0t = g & 31;
    n0t = g >> 5;
  }
  const int m0 = m0t * 128, n0 = n0t * 128;
  const int lane = threadIdx.x & 63, wave = threadIdx.x >> 6;
  const int quad = lane >> 4, c = lane & 15;
  const int wm = wave >> 1, wn = wave & 1;

  // staging: call q stages rows wave*32+q*8 .. +7 (8 rows x 8 chunks = 64 lanes)
  const int srow = lane >> 3, schunk = lane & 7;
  int soff[4];  u16 *lA[4], *lB[4];
  #pragma unroll
  for (int q = 0; q < 4; ++q) {
    int r = wave * 32 + q * 8 + srow;
    soff[q] = r * 1024 + ((schunk ^ (r & 7)) << 3);
    lA[q] = &Als[(wave * 32 + q * 8) * 64 + lane * 8];
    lB[q] = &Bls[(wave * 32 + q * 8) * 64 + lane * 8];
  }
  const u16* gA = A + (size_t)m0 * 1024;
  const u16* gB = BT + (size_t)n0 * 1024;

  int ar[2][4], br[2][4];
  #pragma unroll
  for (int ko = 0; ko < 2; ++ko) {
    #pragma unroll
    for (int i = 0; i < 4; ++i) {
      int rowa = wm * 64 + i * 16 + c;
      ar[ko][i] = rowa * 64 + (((ko * 4 + quad) ^ (rowa & 7)) << 3);
      int rowb = wn * 64 + i * 16 + c;
      br[ko][i] = rowb * 64 + (((ko * 4 + quad) ^ (rowb & 7)) << 3);
    }
  }

  float4_t acc[4][4] = {};
  for (int k0 = 0; k0 < 1024; k0 += 64) {
    #pragma unroll
    for (int q = 0; q < 4; ++q) async16(gA + soff[q] + k0, lA[q]);
    #pragma unroll
    for (int q = 0; q < 4; ++q) async16(gB + soff[q] + k0, lB[q]);
    __syncthreads();
    #pragma unroll
    for (int ko = 0; ko < 2; ++ko) {
      short8_t af[4], bfr[4];
      #pragma unroll
      for (int i = 0; i < 4; ++i) af[i] = *(const short8_t*)&Als[ar[ko][i]];
      #pragma unroll
      for (int j = 0; j < 4; ++j) bfr[j] = *(const short8_t*)&Bls[br[ko][j]];
      #pragma unroll
      for (int i = 0; i < 4; ++i)
        #pragma unroll
        for (int j = 0; j < 4; ++j)
          acc[i][j] = __builtin_amdgcn_mfma_f32_16x16x32_bf16(af[i], bfr[j], acc[i][j], 0, 0, 0);
    }
    __syncthreads();
  }

  const int mrow = m0 + wm * 64, ncol = n0 + wn * 64;
  if (mode == 3) {
    float* o = (float*)o0;
    #pragma unroll
    for (int i = 0; i < 4; ++i) {
      #pragma unroll
      for (int j = 0; j < 4; ++j) {
        int colb = ncol + j * 16 + c;
        float bv = bias0[colb];
        int rowb = mrow + i * 16 + quad * 4;
        #pragma unroll
        for (int r = 0; r < 4; ++r)
          o[(size_t)(rowb + r) * 1024 + colb] = acc[i][j][r] + bv;
      }
    }
  } else {
    #pragma unroll
    for (int j = 0; j < 4; ++j) {
      int colb = ncol + j * 16 + c;     // 0..3071
      int which = colb >> 10;           // 0:Q 1:K 2:V (uniform per j)
      int n1 = colb & 1023, h = n1 >> 6, d = n1 & 63;
      const float* bp = (which == 0) ? bias0 : (which == 1 ? bias1 : bias2);
      float bv = bp[n1];
      #pragma unroll
      for (int i = 0; i < 4; ++i) {
        int rowb = mrow + i * 16 + quad * 4;
        int b = rowb >> 11, s = rowb & 2047;
        if (which == 2) {
          u16* o = (u16*)o2 + (((size_t)(b * 16 + h) * 64 + d) * 2048 + s);
          union { u32 u[2]; u64 ll; } ov;
          ov.u[0] = packbf(acc[i][j][0] + bv, acc[i][j][1] + bv);
          ov.u[1] = packbf(acc[i][j][2] + bv, acc[i][j][3] + bv);
          *(u64*)o = ov.ll;
        } else {
          float sc = (which == 0) ? 0.125f : 1.0f;
          u16* o = (u16*)((which == 0) ? o0 : o1);
          #pragma unroll
          for (int r = 0; r < 4; ++r)
            o[(((size_t)(b * 16 + h) * 2048 + (s + r)) << 6) + d] = f2bf((acc[i][j][r] + bv) * sc);
        }
      }
    }
  }
}

// ---------- softmax: S^T C-layout fragments -> p[8] + row-sum (fixed-base exp) ----------
__device__ inline void softmax_p(float4_t s0, float4_t s1, float4_t mpl0, float4_t mpl1,
                                 bool diag, int kbase, int quad, int c, int qg,
                                 float& lacc, float* p) {
  const float LOG2E = 1.4426950408889634f;
  #pragma unroll
  for (int e = 0; e < 8; ++e) {
    float sv = (e < 4) ? s0[e] : s1[e - 4];
    float ml = (e < 4) ? mpl0[e] : mpl1[e - 4];
    float arg = __builtin_fmaf(sv, LOG2E, ml);
    if (diag) {
      int kpos = kbase + ((e >> 2) << 4) + quad * 4 + (e & 3);
      arg = (kpos > qg) ? -50.0f : arg;   // exp2(-50) ~ 9e-16 ~ 0
    }
    float pe = exp2f(arg);
    p[e] = pe;
    lacc += pe;
  }
}

// P^T C-layout -> 16x16x32 B-operand layout via packed-bf16 shuffles
__device__ inline short8_t p_to_b32(const float* p, int quad, int c) {
  u32 pk0[2] = {packbf(p[0], p[1]), packbf(p[2], p[3])};
  u32 pk1[2] = {packbf(p[4], p[5]), packbf(p[6], p[7])};
  int base = ((quad & 1) * 2) * 16 + c;
  union { u32 u[4]; short8_t v; } pf;
  #pragma unroll
  for (int x = 0; x < 4; ++x) {
    int src = base + ((x >> 1) << 4);
    int v0 = __shfl((int)pk0[x & 1], src);
    int v1 = __shfl((int)pk1[x & 1], src);
    pf.u[x] = (quad < 2) ? (u32)v0 : (u32)v1;
  }
  return pf.v;
}

// ---------- flash attention: 8-wave blocks, 8-way K-split ----------
// Q,K: [B,H,S,64] bf16 (Q pre-scaled 1/8); VT: [B,H,64,S]; ctx: [B,S,1024] bf16.
// Grid 2048 x 512 threads: block = one (bh, 32-query unit); u = 63-(g>>5) -> heavy
// units dispatch first; g&7 pins each bh's K/V to one XCD's L2. 8 waves split K
// strided-by-8 -> per-wave serial chain <= 8 iterations (was 16 at 4 waves).
// Fixed-base softmax (no running max; masked scores -> exp2(-large) = 0) makes
// partials additively combinable; combine via 34.8 KB LDS in two phases
// (waves 0-3 reduce query rows q0..q0+15, waves 4-7 reduce q0+16..q0+31).
__global__ __launch_bounds__(512) void attn_kernel(const u16* __restrict__ Q, const u16* __restrict__ K,
                                                   const u16* __restrict__ VT, const float* __restrict__ mask,
                                                   u16* __restrict__ ctx) {
  __shared__ float cmb[8][64][17];
  const float C1 = 10000.0f * 1.4426950408889634f;
  int w = threadIdx.x >> 6, lane = threadIdx.x & 63;
  int quad = lane >> 4, c = lane & 15;
  int g = blockIdx.x;
  int bh = (g & 7) * 4 + ((g >> 3) & 3);   // XCD-affine
  int u = 63 - (g >> 5);                    // heavy first
  int b = bh >> 4, h = bh & 15;
  const u16* Kp = K + ((size_t)bh << 17);
  const u16* Vp = VT + ((size_t)bh << 17);
  const float* mp = mask + (b << 11);

  int q0 = u << 5;
  const u16* Qp = Q + (((size_t)bh * 2048 + q0 + c) << 6) + quad * 8;
  short8_t qA0 = *(const short8_t*)(Qp);
  short8_t qA1 = *(const short8_t*)(Qp + 32);
  short8_t qB0 = *(const short8_t*)(Qp + 1024);
  short8_t qB1 = *(const short8_t*)(Qp + 1024 + 32);
  float4_t OA[4] = {}, OB[4] = {};
  float lA = 0.0f, lB = 0.0f;
  int qgA = q0 + c, qgB = q0 + 16 + c;
  for (int t = w; t <= u; t += 8) {
    int kbase = t << 5;
    // issue all loads up front
    const u16* kp = Kp + (((size_t)kbase + c) << 6) + quad * 8;
    short8_t ka0 = *(const short8_t*)(kp);
    short8_t ka1 = *(const short8_t*)(kp + 32);
    short8_t kb0 = *(const short8_t*)(kp + 1024);
    short8_t kb1 = *(const short8_t*)(kp + 1024 + 32);
    const u16* vp = Vp + (size_t)c * 2048 + kbase + quad * 8;
    short8_t vf0 = *(const short8_t*)(vp);
    short8_t vf1 = *(const short8_t*)(vp + 16 * 2048);
    short8_t vf2 = *(const short8_t*)(vp + 32 * 2048);
    short8_t vf3 = *(const short8_t*)(vp + 48 * 2048);
    float4_t mv0 = *(const float4_t*)(mp + kbase + quad * 4);
    float4_t mv1 = *(const float4_t*)(mp + kbase + 16 + quad * 4);
    float4_t mpl0 = (mv0 - 1.0f) * C1;  // (1-m)*-10000*log2e
    float4_t mpl1 = (mv1 - 1.0f) * C1;
    bool diag = (t == u);
    // S^T = K_tile @ Q^T
    float4_t sA0 = {}, sA1 = {}, sB0 = {}, sB1 = {};
    sA0 = __builtin_amdgcn_mfma_f32_16x16x32_bf16(ka0, qA0, sA0, 0, 0, 0);
    sA0 = __builtin_amdgcn_mfma_f32_16x16x32_bf16(ka1, qA1, sA0, 0, 0, 0);
    sA1 = __builtin_amdgcn_mfma_f32_16x16x32_bf16(kb0, qA0, sA1, 0, 0, 0);
    sA1 = __builtin_amdgcn_mfma_f32_16x16x32_bf16(kb1, qA1, sA1, 0, 0, 0);
    sB0 = __builtin_amdgcn_mfma_f32_16x16x32_bf16(ka0, qB0, sB0, 0, 0, 0);
    sB0 = __builtin_amdgcn_mfma_f32_16x16x32_bf16(ka1, qB1, sB0, 0, 0, 0);
    sB1 = __builtin_amdgcn_mfma_f32_16x16x32_bf16(kb0, qB0, sB1, 0, 0, 0);
    sB1 = __builtin_amdgcn_mfma_f32_16x16x32_bf16(kb1, qB1, sB1, 0, 0, 0);
    float pA[8], pB[8];
    softmax_p(sA0, sA1, mpl0, mpl1, diag, kbase, quad, c, qgA, lA, pA);
    softmax_p(sB0, sB1, mpl0, mpl1, diag, kbase, quad, c, qgB, lB, pB);
    short8_t pfA = p_to_b32(pA, quad, c);
    short8_t pfB = p_to_b32(pB, quad, c);
    // ctx^T += V^T_tile @ P^T
    OA[0] = __builtin_amdgcn_mfma_f32_16x16x32_bf16(vf0, pfA, OA[0], 0, 0, 0);
    OA[1] = __builtin_amdgcn_mfma_f32_16x16x32_bf16(vf1, pfA, OA[1], 0, 0, 0);
    OA[2] = __builtin_amdgcn_mfma_f32_16x16x32_bf16(vf2, pfA, OA[2], 0, 0, 0);
    OA[3] = __builtin_amdgcn_mfma_f32_16x16x32_bf16(vf3, pfA, OA[3], 0, 0, 0);
    OB[0] = __builtin_amdgcn_mfma_f32_16x16x32_bf16(vf0, pfB, OB[0], 0, 0, 0);
    OB[1] = __builtin_amdgcn_mfma_f32_16x16x32_bf16(vf1, pfB, OB[1], 0, 0, 0);
    OB[2] = __builtin_amdgcn_mfma_f32_16x16x32_bf16(vf2, pfB, OB[2], 0, 0, 0);
    OB[3] = __builtin_amdgcn_mfma_f32_16x16x32_bf16(vf3, pfB, OB[3], 0, 0, 0);
  }
  // ---- combine half A (waves 0-3 reduce) ----
  float* cw = &cmb[w][lane][0];
  #pragma unroll
  for (int d = 0; d < 4; ++d)
    #pragma unroll
    for (int r = 0; r < 4; ++r) cw[d * 4 + r] = OA[d][r];
  cw[16] = lA;
  __syncthreads();
  if (w < 4) {
    float4_t s = {};
    float la = 0.0f;
    #pragma unroll
    for (int w2 = 0; w2 < 8; ++w2) {
      const float* cr = &cmb[w2][lane][0];
      #pragma unroll
      for (int r = 0; r < 4; ++r) s[r] += cr[w * 4 + r];
      la += cr[16];
    }
    la += __shfl_xor(la, 16); la += __shfl_xor(la, 32);
    float rA = 1.0f / la;
    u16* op = ctx + ((size_t)(b * 2048 + q0 + c) * 1024 + h * 64 + w * 16 + quad * 4);
    union { u32 uu[2]; u64 ll; } ov;
    ov.uu[0] = packbf(s[0] * rA, s[1] * rA);
    ov.uu[1] = packbf(s[2] * rA, s[3] * rA);
    *(u64*)op = ov.ll;
  }
  __syncthreads();
  // ---- combine half B (waves 4-7 reduce) ----
  #pragma unroll
  for (int d = 0; d < 4; ++d)
    #pragma unroll
    for (int r = 0; r < 4; ++r) cw[d * 4 + r] = OB[d][r];
  cw[16] = lB;
  __syncthreads();
  if (w >= 4) {
    int dblk = w - 4;
    float4_t s = {};
    float lb = 0.0f;
    #pragma unroll
    for (int w2 = 0; w2 < 8; ++w2) {
      const float* cr = &cmb[w2][lane][0];
      #pragma unroll
      for (int r = 0; r < 4; ++r) s[r] += cr[dblk * 4 + r];
      lb += cr[16];
    }
    lb += __shfl_xor(lb, 16); lb += __shfl_xor(lb, 32);
    float rB = 1.0f / lb;
    u16* op = ctx + ((size_t)(b * 2048 + q0 + 16 + c) * 1024 + h * 64 + dblk * 16 + quad * 4);
    union { u32 uu[2]; u64 ll; } ov;
    ov.uu[0] = packbf(s[0] * rB, s[1] * rB);
    ov.uu[1] = packbf(s[2] * rB, s[3] * rB);
    *(u64*)op = ov.ll;
  }
}

// ---------- launch ----------
extern "C" void kernel_launch(void* const* d_in, const int* in_sizes, int n_in,
                              void* d_out, int out_size, void* d_ws, size_t ws_size,
                              hipStream_t stream) {
  const float* X    = (const float*)d_in[0];
  const float* mask = (const float*)d_in[1];
  const float* Wq   = (const float*)d_in[2];
  const float* bq   = (const float*)d_in[3];
  const float* Wk   = (const float*)d_in[4];
  const float* bk   = (const float*)d_in[5];
  const float* Wv   = (const float*)d_in[6];
  const float* bv   = (const float*)d_in[7];
  const float* Wo   = (const float*)d_in[8];
  const float* bo   = (const float*)d_in[9];

  char* w = (char*)d_ws;
  u16* Xb     = (u16*)(w);                 // 8 MB  [4096,1024] bf16
  u16* WqkvT  = (u16*)(w + (8ull  << 20)); // 6 MB  [3072,1024] bf16 (Q|K|V transposed)
  u16* WoT    = (u16*)(w + (14ull << 20)); // 2 MB  [1024,1024] bf16
  u16* Qb     = (u16*)(w + (16ull << 20)); // 8 MB [B,H,S,64]
  u16* Kb     = (u16*)(w + (24ull << 20)); // 8 MB [B,H,S,64]
  u16* VTb    = (u16*)(w + (32ull << 20)); // 8 MB [B,H,64,S]
  u16* Ctx    = (u16*)(w + (40ull << 20)); // 8 MB [4096,1024]

  prologue<<<8192, 256, 0, stream>>>(X, Wq, Wk, Wv, Wo, Xb, WqkvT, WoT);
  gemm128<<<768, 256, 0, stream>>>(Xb, WqkvT, bq, bk, bv, Qb, Kb, VTb, 4);
  attn_kernel<<<2048, 512, 0, stream>>>(Qb, Kb, VTb, mask, Ctx);
  gemm128<<<256, 256, 0, stream>>>(Ctx, WoT, bo, bo, bo, d_out, d_out, d_out, 3);
}